// Round 8
// baseline (549.096 us; speedup 1.0000x reference)
//
#include <hip/hip_runtime.h>
#include <math.h>

// LIF_13984413516471 — exact serial chain, wave-cooperative staging,
// register-pinned window prefetch. B=128, S=128, H=128, K=8.
// Reference: one scalar accumulator per batch, sequential over (i,j,k);
// per substep: s += x; if (s > th[k]) s = 0.
// Outputs (B,S,K,H) fp32: outs | spikes. Bitwise-exact fp32 replay.

#define NB 128
#define NS 128
#define NH 128
#define NK 8
#define NT (NS * NH)            // 16384 t per batch
#define WL 8                    // vote window = 8 t
#define NW2 (NT / WL)           // 2048 windows per batch
#define SWT 256                 // superwindow = 256 t = 32 windows
#define NSW (NT / SWT)          // 64 superwindows
#define NP (NSW / 2)            // 32 pairs (pair = 64 windows = 512 t)
#define OUTN ((size_t)NB * NS * NK * NH)

// ---- ws layout (floats) ----
#define WS_M     0                      // M    [NB][NW2]
#define WS_SENT  (NB * NW2)             // s_ent[NB][NW2]  (window-entry states)
#define WS_TOTAL (2 * NB * NW2)

// Per-(b,window) quiet bound, f64: M = minth - maxPrefix - margin where
// maxPrefix >= max prefix sum of the 64 substep adds from window entry.
// If entering s <= M, the real-arith chain stays >= margin below minth all
// window; fp32 drift over 64 adds at |s|<=26000 is < 0.1 = margin, so the
// fp32 chain provably never spikes -> pure adds are bitwise-exact.
__global__ void lif_bounds8(const float* __restrict__ x,
                            const float* __restrict__ th,
                            float* __restrict__ M)
{
    int idx = blockIdx.x * 256 + threadIdx.x;   // flat over NB*NW2
    if (idx >= NB * NW2) return;
    float minth = th[0];
#pragma unroll
    for (int k = 1; k < NK; ++k) minth = fminf(minth, th[k]);
    const float* xp = x + (size_t)idx * WL;     // idx = b*NW2 + w -> x[b][w*8]
    double p = 0.0, maxp = -1e300;
#pragma unroll
    for (int l = 0; l < WL; ++l) {
        double xv = (double)xp[l];
#pragma unroll
        for (int k = 0; k < NK; ++k) { p += xv; maxp = fmax(maxp, p); }
    }
    M[idx] = (float)((double)minth - maxp - 0.1 - 1e-6 * fabs(maxp));
}

#define ADD8(xv) do { s += xv; s += xv; s += xv; s += xv; \
                      s += xv; s += xv; s += xv; s += xv; } while (0)
#define STEP8(xv) do { \
    s += xv; s = (s > th0) ? 0.0f : s; \
    s += xv; s = (s > th1) ? 0.0f : s; \
    s += xv; s = (s > th2) ? 0.0f : s; \
    s += xv; s = (s > th3) ? 0.0f : s; \
    s += xv; s = (s > th4) ? 0.0f : s; \
    s += xv; s = (s > th5) ? 0.0f : s; \
    s += xv; s = (s > th6) ? 0.0f : s; \
    s += xv; s = (s > th7) ? 0.0f : s; } while (0)

// Chain: 1 batch per 64-thread block (1 wave). All lanes run the scalar
// chain redundantly; x/M arrive via coalesced wave loads -> LDS ->
// same-address broadcast ds_read_b128 (conflict-free). Next window's x is
// prefetched into NAMED registers and pinned live via an empty asm at the
// END of the window body (completion waits land where the 256-cyc add
// chain has already hidden the LDS latency). Quiet windows: pure adds
// (bitwise identical, certified). Per-window entering states collect in
// lane registers (cndmask) and store once per 64 windows, coalesced.
__global__ void __launch_bounds__(64, 1)
lif_chain(const float* __restrict__ x, const float* __restrict__ th,
          const float* __restrict__ M, float* __restrict__ s_ent)
{
    __shared__ float4 xs4[SWT / 4];   // current superwindow's x (64 float4)
    __shared__ float  Ms[64];         // current pair's 64 window bounds

    const int b = blockIdx.x;
    const int lane = threadIdx.x;
    const float4* xb4 = (const float4*)(x + (size_t)b * NT);
    const float*  Mb  = M + (size_t)b * NW2;
    float* seb = s_ent + (size_t)b * NW2;

    const float th0 = th[0], th1 = th[1], th2 = th[2], th3 = th[3];
    const float th4 = th[4], th5 = th[5], th6 = th[6], th7 = th[7];

    float s = 0.0f, keep = 0.0f;
    float4 lx = xb4[lane];      // superwindow 0 staging (1 float4/lane)
    float  lm = Mb[lane];       // pair 0 bounds (1 float/lane)

    for (int p = 0; p < NP; ++p) {
        Ms[lane] = lm;                                   // publish pair p
        lm = Mb[(size_t)((p + 1 < NP) ? p + 1 : p) * 64 + lane];  // prefetch p+1
#pragma unroll
        for (int half = 0; half < 2; ++half) {
            const int sw = 2 * p + half;
            xs4[lane] = lx;                              // publish sw
            lx = xb4[(size_t)((sw + 1 < NSW) ? sw + 1 : sw) * 64 + lane]; // prefetch
            const int mbase = half * 32;

            // window 0 of this half: current regs
            float4 c0 = xs4[0], c1 = xs4[1];
            float x0 = c0.x, x1 = c0.y, x2 = c0.z, x3 = c0.w;
            float x4 = c1.x, x5 = c1.y, x6 = c1.z, x7 = c1.w;
            float Mc = Ms[mbase];

            for (int wi = 0; wi < 32; ++wi) {
                const int nwi = (wi + 1) & 31;
                // prefetch next window into named regs (pinned below)
                float4 t0 = xs4[2 * nwi], t1 = xs4[2 * nwi + 1];
                float n0 = t0.x, n1 = t0.y, n2 = t0.z, n3 = t0.w;
                float n4 = t1.x, n5 = t1.y, n6 = t1.z, n7 = t1.w;
                float Mn = Ms[mbase + nwi];   // wi=31: dummy (re-read next sw)

                keep = (lane == mbase + wi) ? s : keep;
                int q = __builtin_amdgcn_readfirstlane((int)(s <= Mc));
                if (q) {
                    // certified spike-free window: bitwise-identical pure adds
                    ADD8(x0); ADD8(x1); ADD8(x2); ADD8(x3);
                    ADD8(x4); ADD8(x5); ADD8(x6); ADD8(x7);
                } else {
                    STEP8(x0); STEP8(x1); STEP8(x2); STEP8(x3);
                    STEP8(x4); STEP8(x5); STEP8(x6); STEP8(x7);
                }
                // pin prefetched values into VGPRs at the join point:
                // lgkmcnt wait lands here, after the add chain hid it.
                asm volatile("" : "+v"(n0), "+v"(n1), "+v"(n2), "+v"(n3),
                                  "+v"(n4), "+v"(n5), "+v"(n6), "+v"(n7),
                                  "+v"(Mn));
                x0 = n0; x1 = n1; x2 = n2; x3 = n3;
                x4 = n4; x5 = n5; x6 = n6; x7 = n7;
                Mc = Mn;
            }
        }
        seb[(size_t)p * 64 + lane] = keep;               // 64 windows, coalesced
    }
}

// Output pass: fully parallel, no serial section. block = (b, i), thread j.
// Lane j replays (j&7) t-steps from its window's entering state, then emits
// its own t's 8 outputs, coalesced per k-plane. Bitwise-exact replay.
__global__ void __launch_bounds__(128)
lif_out(const float* __restrict__ x, const float* __restrict__ th,
        const float* __restrict__ s_ent, float* __restrict__ out)
{
    const int j = threadIdx.x;             // 0..127
    const int i = blockIdx.x & (NS - 1);
    const int b = blockIdx.x >> 7;
    const int wl = j >> 3;                 // window within row (0..15)
    const int r  = j & 7;                  // position within window

    const float th0 = th[0], th1 = th[1], th2 = th[2], th3 = th[3];
    const float th4 = th[4], th5 = th[5], th6 = th[6], th7 = th[7];

    float s = s_ent[(size_t)b * NW2 + i * 16 + wl];
    const float* xrow = x + (size_t)b * NT + i * NH + (wl << 3);

    for (int m = 0; m < r; ++m) {          // replay to own t (<=7 steps)
        float xv = xrow[m];
        STEP8(xv);
    }
    float xv = xrow[r];

    float* o  = out + (((size_t)b * NS + i) * NK) * NH + j;
    float* sp = o + OUTN;
    float thr[NK];
#pragma unroll
    for (int k = 0; k < NK; ++k) thr[k] = th[k];
#pragma unroll
    for (int k = 0; k < NK; ++k) {
        s += xv;
        bool spike = s > thr[k];
        o[(size_t)k * NH]  = spike ? s : 0.0f;
        sp[(size_t)k * NH] = spike ? 1.0f : 0.0f;
        s = spike ? 0.0f : s;
    }
}

// Fallback if ws is too small: single-pass, scattered writes (slow, correct).
__global__ void lif_mono(const float* __restrict__ x, const float* __restrict__ th,
                         float* __restrict__ out)
{
    int b = blockIdx.x * 64 + threadIdx.x;
    if (b >= NB) return;
    float thr[NK];
#pragma unroll
    for (int k = 0; k < NK; ++k) thr[k] = th[k];
    const float* xb = x + (size_t)b * NT;
    float s = 0.0f;
    for (int i = 0; i < NS; ++i)
        for (int j = 0; j < NH; ++j) {
            float xv = xb[i * NH + j];
#pragma unroll
            for (int k = 0; k < NK; ++k) {
                s += xv;
                bool spike = s > thr[k];
                size_t idx = (((size_t)b * NS + i) * NK + k) * NH + j;
                out[idx]        = spike ? s : 0.0f;
                out[OUTN + idx] = spike ? 1.0f : 0.0f;
                s = spike ? 0.0f : s;
            }
        }
}

extern "C" void kernel_launch(void* const* d_in, const int* in_sizes, int n_in,
                              void* d_out, int out_size, void* d_ws, size_t ws_size,
                              hipStream_t stream) {
    const float* x  = (const float*)d_in[0];   // (128,128,128) fp32
    const float* th = (const float*)d_in[1];   // (8,) fp32
    float* out = (float*)d_out;

    if (ws_size >= (size_t)WS_TOTAL * sizeof(float)) {
        float* ws    = (float*)d_ws;
        float* Mbuf  = ws + WS_M;
        float* s_ent = ws + WS_SENT;

        lif_bounds8<<<dim3((NB * NW2 + 255) / 256), dim3(256), 0, stream>>>(x, th, Mbuf);
        lif_chain<<<dim3(NB), dim3(64), 0, stream>>>(x, th, Mbuf, s_ent);
        lif_out<<<dim3(NB * NS), dim3(128), 0, stream>>>(x, th, s_ent, out);
    } else {
        lif_mono<<<dim3(2), dim3(64), 0, stream>>>(x, th, out);
    }
}

// Round 9
// 464.199 us; speedup vs baseline: 1.1829x; 1.1829x over previous
//
#include <hip/hip_runtime.h>
#include <math.h>

// LIF_13984413516471 — exact serial chain; x/M staged in lane registers and
// broadcast to the chain via v_readlane (no LDS, no memory op on the
// critical path). B=128, S=128, H=128, K=8.
// Reference: one scalar accumulator per batch, sequential over (i,j,k);
// per substep: s += x; if (s > th[k]) s = 0.
// Outputs (B,S,K,H) fp32: outs | spikes. Bitwise-exact fp32 replay.

#define NB 128
#define NS 128
#define NH 128
#define NK 8
#define NT (NS * NH)            // 16384 t per batch
#define WL 8                    // vote window = 8 t
#define NW2 (NT / WL)           // 2048 windows per batch
#define NG64 (NT / 64)          // 256 x-groups (64 t = 8 windows each)
#define NP64 (NW2 / 64)         // 32 M-groups (64 windows = 512 t each)
#define OUTN ((size_t)NB * NS * NK * NH)

// ---- ws layout (floats) ----
#define WS_M     0                      // M    [NB][NW2]
#define WS_SENT  (NB * NW2)             // s_ent[NB][NW2]  (window-entry states)
#define WS_TOTAL (2 * NB * NW2)

// Per-(b,window) quiet bound, f64: M = minth - maxPrefix - margin where
// maxPrefix >= max prefix sum of the 64 substep adds from window entry.
// If entering s <= M, the real-arith chain stays >= margin below minth all
// window; fp32 drift over 64 adds at |s|<=26000 is < 0.1 = margin, so the
// fp32 chain provably never spikes -> pure adds are bitwise-exact.
__global__ void lif_bounds8(const float* __restrict__ x,
                            const float* __restrict__ th,
                            float* __restrict__ M)
{
    int idx = blockIdx.x * 256 + threadIdx.x;   // flat over NB*NW2
    if (idx >= NB * NW2) return;
    float minth = th[0];
#pragma unroll
    for (int k = 1; k < NK; ++k) minth = fminf(minth, th[k]);
    const float* xp = x + (size_t)idx * WL;     // idx = b*NW2 + w -> x[b][w*8]
    double p = 0.0, maxp = -1e300;
#pragma unroll
    for (int l = 0; l < WL; ++l) {
        double xv = (double)xp[l];
#pragma unroll
        for (int k = 0; k < NK; ++k) { p += xv; maxp = fmax(maxp, p); }
    }
    M[idx] = (float)((double)minth - maxp - 0.1 - 1e-6 * fabs(maxp));
}

#define ADD8(xv) do { s += xv; s += xv; s += xv; s += xv; \
                      s += xv; s += xv; s += xv; s += xv; } while (0)
#define STEP8(xv) do { \
    s += xv; s = (s > th0) ? 0.0f : s; \
    s += xv; s = (s > th1) ? 0.0f : s; \
    s += xv; s = (s > th2) ? 0.0f : s; \
    s += xv; s = (s > th3) ? 0.0f : s; \
    s += xv; s = (s > th4) ? 0.0f : s; \
    s += xv; s = (s > th5) ? 0.0f : s; \
    s += xv; s = (s > th6) ? 0.0f : s; \
    s += xv; s = (s > th7) ? 0.0f : s; } while (0)

// readlane broadcast: lane-register -> SGPR (uniform), no wait counters.
__device__ __forceinline__ float rl(float v, int idx) {
    return __int_as_float(__builtin_amdgcn_readlane(__float_as_int(v), idx));
}

// Chain: 1 batch per 64-thread block (1 wave); all lanes run the scalar
// chain redundantly. Lane l of x-group g holds x[g*64+l]; window wi uses
// readlane(cx, wi*8+m) -> SGPR operand of the dependent v_add_f32 chain.
// One coalesced global load per 8 windows (double-buffered one group
// ahead); one M load per 64 windows. Vote via readfirstlane -> s_cbranch.
// Window-entry states collect per lane (cndmask) -> one coalesced store
// per 64 windows.
__global__ void __launch_bounds__(64, 1)
lif_chain(const float* __restrict__ x, const float* __restrict__ th,
          const float* __restrict__ M, float* __restrict__ s_ent)
{
    const int b = blockIdx.x;
    const int lane = threadIdx.x;
    const float* xb = x + (size_t)b * NT;
    const float* Mb = M + (size_t)b * NW2;
    float* seb = s_ent + (size_t)b * NW2;

    const float th0 = th[0], th1 = th[1], th2 = th[2], th3 = th[3];
    const float th4 = th[4], th5 = th[5], th6 = th[6], th7 = th[7];

    float s = 0.0f, keep = 0.0f;
    float cx = xb[lane];        // x-group 0 (64 t = 8 windows)
    float cM = Mb[lane];        // M-group 0 (64 windows)

    for (int p = 0; p < NP64; ++p) {
        float nM = Mb[(size_t)((p + 1 < NP64) ? p + 1 : p) * 64 + lane];
        for (int g8 = 0; g8 < 8; ++g8) {
            const int gg = p * 8 + g8;
            float nx = xb[(size_t)((gg + 1 < NG64) ? gg + 1 : gg) * 64 + lane];
#pragma unroll
            for (int wi = 0; wi < 8; ++wi) {
                const int wpi = g8 * 8 + wi;            // window within M-group
                float Mc = rl(cM, wpi);                 // uniform dynamic index
                float x0 = rl(cx, wi * 8 + 0), x1 = rl(cx, wi * 8 + 1);
                float x2 = rl(cx, wi * 8 + 2), x3 = rl(cx, wi * 8 + 3);
                float x4 = rl(cx, wi * 8 + 4), x5 = rl(cx, wi * 8 + 5);
                float x6 = rl(cx, wi * 8 + 6), x7 = rl(cx, wi * 8 + 7);
                keep = (lane == wpi) ? s : keep;
                int q = __builtin_amdgcn_readfirstlane((int)(s <= Mc));
                if (q) {
                    // certified spike-free window: bitwise-identical pure adds
                    ADD8(x0); ADD8(x1); ADD8(x2); ADD8(x3);
                    ADD8(x4); ADD8(x5); ADD8(x6); ADD8(x7);
                } else {
                    STEP8(x0); STEP8(x1); STEP8(x2); STEP8(x3);
                    STEP8(x4); STEP8(x5); STEP8(x6); STEP8(x7);
                }
            }
            cx = nx;
        }
        seb[(size_t)p * 64 + lane] = keep;              // coalesced, 1/64 windows
        cM = nM;
    }
}

// Output pass: fully parallel, no serial section. block = (b, i), thread j.
// Lane j replays (j&7) t-steps from its window's entering state, then emits
// its own t's 8 outputs, coalesced per k-plane. Bitwise-exact replay.
__global__ void __launch_bounds__(128)
lif_out(const float* __restrict__ x, const float* __restrict__ th,
        const float* __restrict__ s_ent, float* __restrict__ out)
{
    const int j = threadIdx.x;             // 0..127
    const int i = blockIdx.x & (NS - 1);
    const int b = blockIdx.x >> 7;
    const int wl = j >> 3;                 // window within row (0..15)
    const int r  = j & 7;                  // position within window

    const float th0 = th[0], th1 = th[1], th2 = th[2], th3 = th[3];
    const float th4 = th[4], th5 = th[5], th6 = th[6], th7 = th[7];

    float s = s_ent[(size_t)b * NW2 + i * 16 + wl];
    const float* xrow = x + (size_t)b * NT + i * NH + (wl << 3);

    for (int m = 0; m < r; ++m) {          // replay to own t (<=7 steps)
        float xv = xrow[m];
        STEP8(xv);
    }
    float xv = xrow[r];

    float* o  = out + (((size_t)b * NS + i) * NK) * NH + j;
    float* sp = o + OUTN;
    float thr[NK];
#pragma unroll
    for (int k = 0; k < NK; ++k) thr[k] = th[k];
#pragma unroll
    for (int k = 0; k < NK; ++k) {
        s += xv;
        bool spike = s > thr[k];
        o[(size_t)k * NH]  = spike ? s : 0.0f;
        sp[(size_t)k * NH] = spike ? 1.0f : 0.0f;
        s = spike ? 0.0f : s;
    }
}

// Fallback if ws is too small: single-pass, scattered writes (slow, correct).
__global__ void lif_mono(const float* __restrict__ x, const float* __restrict__ th,
                         float* __restrict__ out)
{
    int b = blockIdx.x * 64 + threadIdx.x;
    if (b >= NB) return;
    float thr[NK];
#pragma unroll
    for (int k = 0; k < NK; ++k) thr[k] = th[k];
    const float* xb = x + (size_t)b * NT;
    float s = 0.0f;
    for (int i = 0; i < NS; ++i)
        for (int j = 0; j < NH; ++j) {
            float xv = xb[i * NH + j];
#pragma unroll
            for (int k = 0; k < NK; ++k) {
                s += xv;
                bool spike = s > thr[k];
                size_t idx = (((size_t)b * NS + i) * NK + k) * NH + j;
                out[idx]        = spike ? s : 0.0f;
                out[OUTN + idx] = spike ? 1.0f : 0.0f;
                s = spike ? 0.0f : s;
            }
        }
}

extern "C" void kernel_launch(void* const* d_in, const int* in_sizes, int n_in,
                              void* d_out, int out_size, void* d_ws, size_t ws_size,
                              hipStream_t stream) {
    const float* x  = (const float*)d_in[0];   // (128,128,128) fp32
    const float* th = (const float*)d_in[1];   // (8,) fp32
    float* out = (float*)d_out;

    if (ws_size >= (size_t)WS_TOTAL * sizeof(float)) {
        float* ws    = (float*)d_ws;
        float* Mbuf  = ws + WS_M;
        float* s_ent = ws + WS_SENT;

        lif_bounds8<<<dim3((NB * NW2 + 255) / 256), dim3(256), 0, stream>>>(x, th, Mbuf);
        lif_chain<<<dim3(NB), dim3(64), 0, stream>>>(x, th, Mbuf, s_ent);
        lif_out<<<dim3(NB * NS), dim3(128), 0, stream>>>(x, th, s_ent, out);
    } else {
        lif_mono<<<dim3(2), dim3(64), 0, stream>>>(x, th, out);
    }
}

// Round 10
// 417.173 us; speedup vs baseline: 1.3162x; 1.1127x over previous
//
#include <hip/hip_runtime.h>
#include <math.h>

// LIF_13984413516471 — exact serial chain; x/M staged in lane registers,
// broadcast via v_readlane; hierarchical (64-t group / 8-t window) certified
// quiet fast paths. B=128, S=128, H=128, K=8.
// Reference: one scalar accumulator per batch, sequential over (i,j,k);
// per substep: s += x; if (s > th[k]) s = 0.
// Outputs (B,S,K,H) fp32: outs | spikes. Bitwise-exact fp32 replay.

#define NB 128
#define NS 128
#define NH 128
#define NK 8
#define NT (NS * NH)            // 16384 t per batch
#define WL 8                    // vote window = 8 t (64 substeps)
#define NW2 (NT / WL)           // 2048 windows per batch
#define NG64 (NT / 64)          // 256 groups (64 t = 8 windows each)
#define NP64 (NW2 / 64)         // 32 store-groups (64 windows = 512 t each)
#define OUTN ((size_t)NB * NS * NK * NH)

// ---- ws layout (floats) ----
#define WS_M     0                            // M    [NB][NW2]
#define WS_M64   (NB * NW2)                   // M64  [NB][NG64]
#define WS_SENT  (NB * NW2 + NB * NG64)       // s_ent[NB][NW2]
#define WS_TOTAL (2 * NB * NW2 + NB * NG64)

// Per-(b,window) and per-(b,group) quiet bounds, f64, RELATIVE to the
// threshold active at each substep: wmax = max_i (prefix_i - th_k(i)).
// Quiet iff entering s <= -wmax - margin: real-arith chain then stays
// >= margin below every active threshold; fp32 drift over n adds at
// |s|<=16384 is n*4.9e-4/2 (64->0.016, 512->0.125), covered by margins
// 0.1 / 0.5 with >=2x slack -> pure adds are bitwise-exact.
__global__ void lif_bounds(const float* __restrict__ x,
                           const float* __restrict__ th,
                           float* __restrict__ M, float* __restrict__ M64)
{
    int idx = blockIdx.x * 256 + threadIdx.x;   // flat over NB*NG64
    if (idx >= NB * NG64) return;
    int b = idx >> 8, gg = idx & (NG64 - 1);
    float t[NK];
#pragma unroll
    for (int k = 0; k < NK; ++k) t[k] = th[k];
    const float* xp = x + (size_t)b * NT + gg * 64;

    double pg = 0.0, gmax = -1e300;
#pragma unroll
    for (int w8 = 0; w8 < 8; ++w8) {
        double pw = 0.0, wmax = -1e300;
#pragma unroll
        for (int l = 0; l < 8; ++l) {
            double xv = (double)xp[w8 * 8 + l];
#pragma unroll
            for (int k = 0; k < NK; ++k) {
                pw += xv;
                double rel = pw - (double)t[k];
                wmax = fmax(wmax, rel);
            }
        }
        gmax = fmax(gmax, pg + wmax);
        pg += pw;
        M[(size_t)b * NW2 + gg * 8 + w8] =
            (float)(-wmax - 0.1 - 1e-6 * fabs(wmax));
    }
    M64[(size_t)b * NG64 + gg] = (float)(-gmax - 0.5 - 1e-6 * fabs(gmax));
}

#define ADD8(xv) do { s += xv; s += xv; s += xv; s += xv; \
                      s += xv; s += xv; s += xv; s += xv; } while (0)
#define STEP8(xv) do { \
    s += xv; s = (s > th0) ? 0.0f : s; \
    s += xv; s = (s > th1) ? 0.0f : s; \
    s += xv; s = (s > th2) ? 0.0f : s; \
    s += xv; s = (s > th3) ? 0.0f : s; \
    s += xv; s = (s > th4) ? 0.0f : s; \
    s += xv; s = (s > th5) ? 0.0f : s; \
    s += xv; s = (s > th6) ? 0.0f : s; \
    s += xv; s = (s > th7) ? 0.0f : s; } while (0)

__device__ __forceinline__ float rl(float v, int idx) {
    return __int_as_float(__builtin_amdgcn_readlane(__float_as_int(v), idx));
}

// Chain: 1 batch per 64-thread block (1 wave); all lanes run the scalar
// chain redundantly. Lane l of x-group g holds x[g*64+l]; values broadcast
// via readlane (SGPR operand of the dependent v_add chain, no wait counters),
// pipelined one sub-block ahead so issue rides the add-latency bubbles.
// Hierarchical vote: group-level (512 substeps, one readfirstlane branch)
// then window-level (64 substeps). Window-entry states collect per lane
// (cndmask) -> one coalesced store per 64 windows.
__global__ void __launch_bounds__(64, 1)
lif_chain(const float* __restrict__ x, const float* __restrict__ th,
          const float* __restrict__ M, const float* __restrict__ M64,
          float* __restrict__ s_ent)
{
    const int b = blockIdx.x;
    const int lane = threadIdx.x;
    const float* xb   = x + (size_t)b * NT;
    const float* Mb   = M + (size_t)b * NW2;
    const float* M64b = M64 + (size_t)b * NG64;
    float* seb = s_ent + (size_t)b * NW2;

    const float th0 = th[0], th1 = th[1], th2 = th[2], th3 = th[3];
    const float th4 = th[4], th5 = th[5], th6 = th[6], th7 = th[7];

    float s = 0.0f, keep = 0.0f;
    float cx   = xb[lane];      // x-group 0 (64 t = 8 windows)
    float cM   = Mb[lane];      // window bounds, store-group 0
    float cM64 = M64b[0];       // group bound 0

    for (int p = 0; p < NP64; ++p) {
        float nM = Mb[(size_t)((p + 1 < NP64) ? p + 1 : p) * 64 + lane];
        for (int g8 = 0; g8 < 8; ++g8) {
            const int gg = p * 8 + g8;
            const int ggn = (gg + 1 < NG64) ? gg + 1 : gg;
            float nx   = xb[(size_t)ggn * 64 + lane];
            float nM64 = M64b[ggn];
            const int wbase = g8 * 8;

            int q64 = __builtin_amdgcn_readfirstlane((int)(s <= cM64));
            if (q64) {
                // certified spike-free 64-t group: 512 bitwise-exact adds
                float xc = rl(cx, 0);
#pragma unroll
                for (int wi = 0; wi < 8; ++wi) {
                    keep = (lane == wbase + wi) ? s : keep;
#pragma unroll
                    for (int m = 0; m < 8; ++m) {
                        int ni = wi * 8 + m + 1; if (ni > 63) ni = 63;
                        float xn = rl(cx, ni);
                        ADD8(xc);
                        xc = xn;
                    }
                }
            } else {
#pragma unroll
                for (int wi = 0; wi < 8; ++wi) {
                    float Mc = rl(cM, wbase + wi);
                    keep = (lane == wbase + wi) ? s : keep;
                    float xc = rl(cx, wi * 8);
                    int q = __builtin_amdgcn_readfirstlane((int)(s <= Mc));
                    if (q) {
                        // certified spike-free window: pure adds
#pragma unroll
                        for (int m = 0; m < 8; ++m) {
                            int ni = wi * 8 + m + 1; if (ni > 63) ni = 63;
                            float xn = rl(cx, ni);
                            ADD8(xc);
                            xc = xn;
                        }
                    } else {
#pragma unroll
                        for (int m = 0; m < 8; ++m) {
                            int ni = wi * 8 + m + 1; if (ni > 63) ni = 63;
                            float xn = rl(cx, ni);
                            STEP8(xc);
                            xc = xn;
                        }
                    }
                }
            }
            cx = nx; cM64 = nM64;
        }
        seb[(size_t)p * 64 + lane] = keep;              // coalesced, 1/64 windows
        cM = nM;
    }
}

// Output pass: fully parallel, no serial section. block = (b, i), thread j.
// Lane j replays (j&7) t-steps from its window's entering state, then emits
// its own t's 8 outputs, coalesced per k-plane. Bitwise-exact replay.
__global__ void __launch_bounds__(128)
lif_out(const float* __restrict__ x, const float* __restrict__ th,
        const float* __restrict__ s_ent, float* __restrict__ out)
{
    const int j = threadIdx.x;             // 0..127
    const int i = blockIdx.x & (NS - 1);
    const int b = blockIdx.x >> 7;
    const int wl = j >> 3;                 // window within row (0..15)
    const int r  = j & 7;                  // position within window

    const float th0 = th[0], th1 = th[1], th2 = th[2], th3 = th[3];
    const float th4 = th[4], th5 = th[5], th6 = th[6], th7 = th[7];

    float s = s_ent[(size_t)b * NW2 + i * 16 + wl];
    const float* xrow = x + (size_t)b * NT + i * NH + (wl << 3);

    for (int m = 0; m < r; ++m) {          // replay to own t (<=7 steps)
        float xv = xrow[m];
        STEP8(xv);
    }
    float xv = xrow[r];

    float* o  = out + (((size_t)b * NS + i) * NK) * NH + j;
    float* sp = o + OUTN;
    float thr[NK];
#pragma unroll
    for (int k = 0; k < NK; ++k) thr[k] = th[k];
#pragma unroll
    for (int k = 0; k < NK; ++k) {
        s += xv;
        bool spike = s > thr[k];
        o[(size_t)k * NH]  = spike ? s : 0.0f;
        sp[(size_t)k * NH] = spike ? 1.0f : 0.0f;
        s = spike ? 0.0f : s;
    }
}

// Fallback if ws is too small: single-pass, scattered writes (slow, correct).
__global__ void lif_mono(const float* __restrict__ x, const float* __restrict__ th,
                         float* __restrict__ out)
{
    int b = blockIdx.x * 64 + threadIdx.x;
    if (b >= NB) return;
    float thr[NK];
#pragma unroll
    for (int k = 0; k < NK; ++k) thr[k] = th[k];
    const float* xb = x + (size_t)b * NT;
    float s = 0.0f;
    for (int i = 0; i < NS; ++i)
        for (int j = 0; j < NH; ++j) {
            float xv = xb[i * NH + j];
#pragma unroll
            for (int k = 0; k < NK; ++k) {
                s += xv;
                bool spike = s > thr[k];
                size_t idx = (((size_t)b * NS + i) * NK + k) * NH + j;
                out[idx]        = spike ? s : 0.0f;
                out[OUTN + idx] = spike ? 1.0f : 0.0f;
                s = spike ? 0.0f : s;
            }
        }
}

extern "C" void kernel_launch(void* const* d_in, const int* in_sizes, int n_in,
                              void* d_out, int out_size, void* d_ws, size_t ws_size,
                              hipStream_t stream) {
    const float* x  = (const float*)d_in[0];   // (128,128,128) fp32
    const float* th = (const float*)d_in[1];   // (8,) fp32
    float* out = (float*)d_out;

    if (ws_size >= (size_t)WS_TOTAL * sizeof(float)) {
        float* ws    = (float*)d_ws;
        float* Mbuf  = ws + WS_M;
        float* M64b  = ws + WS_M64;
        float* s_ent = ws + WS_SENT;

        lif_bounds<<<dim3((NB * NG64 + 255) / 256), dim3(256), 0, stream>>>(x, th, Mbuf, M64b);
        lif_chain<<<dim3(NB), dim3(64), 0, stream>>>(x, th, Mbuf, M64b, s_ent);
        lif_out<<<dim3(NB * NS), dim3(128), 0, stream>>>(x, th, s_ent, out);
    } else {
        lif_mono<<<dim3(2), dim3(64), 0, stream>>>(x, th, out);
    }
}